// Round 1
// 265.221 us; speedup vs baseline: 1.3262x; 1.3262x over previous
//
#include <hip/hip_runtime.h>
#include <math.h>

typedef __attribute__((ext_vector_type(8))) short short8;
typedef __attribute__((ext_vector_type(4))) float f32x4;

#define B_SZ 8192
#define D_INN 4000
#define EMBD 96
#define H0D 2048
#define H1D 1024
#define KDIM 4096  // EMB + D_IN

__device__ __forceinline__ unsigned short f2bf(float f) {
  union { float f; unsigned u; } v; v.f = f;
  unsigned r = v.u + 0x7FFFu + ((v.u >> 16) & 1u);
  return (unsigned short)(r >> 16);
}
__device__ __forceinline__ float bf2f(unsigned short h) {
  union { unsigned u; float f; } v; v.u = ((unsigned)h) << 16;
  return v.f;
}
__device__ __forceinline__ void gld_lds16(const void* g, void* l) {
  __builtin_amdgcn_global_load_lds(
      (const __attribute__((address_space(1))) unsigned int*)g,
      (__attribute__((address_space(3))) unsigned int*)l, 16, 0, 0);
}

// ---- transpose + fp32->bf16 convert: out[c][r] = bf16(in[r][c]) ----
__global__ __launch_bounds__(256) void transpose_cvt(
    const float* __restrict__ in, unsigned short* __restrict__ out, int R, int C) {
  __shared__ float tile[32][33];
  int c0 = blockIdx.x * 32, r0 = blockIdx.y * 32;
  int tc = threadIdx.x & 31, tr = threadIdx.x >> 5;
#pragma unroll
  for (int i = 0; i < 4; ++i) {
    int r = tr + i * 8;
    tile[r][tc] = in[(size_t)(r0 + r) * C + (c0 + tc)];
  }
  __syncthreads();
#pragma unroll
  for (int i = 0; i < 4; ++i) {
    int rr = tr + i * 8;
    out[(size_t)(c0 + rr) * R + (r0 + tc)] = f2bf(tile[tc][rr]);
  }
}

// ---- build A = [emb_gather | inputs] in bf16, vectorized 8-wide ----
__global__ __launch_bounds__(256) void build_A(
    const float* __restrict__ inputs, const float* __restrict__ emb,
    const int* __restrict__ ballot, const int* __restrict__ contest,
    unsigned short* __restrict__ A) {
  int gid = blockIdx.x * 256 + threadIdx.x;   // chunk of 8 elems
  int b = gid >> 9, c = gid & 511;            // 512 chunks per row of 4096
  const float* src;
  if (c < EMBD / 8) {
    int e = ballot[b] * 8 + contest[b];
    src = emb + (size_t)e * EMBD + c * 8;
  } else {
    src = inputs + (size_t)b * D_INN + (c - EMBD / 8) * 8;
  }
  float4 v0 = *(const float4*)src;
  float4 v1 = *(const float4*)(src + 4);
  unsigned short r[8];
  r[0] = f2bf(v0.x); r[1] = f2bf(v0.y); r[2] = f2bf(v0.z); r[3] = f2bf(v0.w);
  r[4] = f2bf(v1.x); r[5] = f2bf(v1.y); r[6] = f2bf(v1.z); r[7] = f2bf(v1.w);
  *reinterpret_cast<short8*>(A + (size_t)b * KDIM + c * 8) =
      *reinterpret_cast<const short8*>(r);
}

// ---- NT bf16 MFMA GEMM, ring-3 pipelined, counted vmcnt ----
// BN = 256 always; BM = MREP*32 (MREP=8 -> 256, MREP=4 -> 128); BK = 32.
// 8 waves = 2 (M) x 4 (N); per-wave output = MREP*16 x 64.
// LDS: A ring 3 x (BM*32) bf16, B ring 3 x (256*32) bf16.
// Staging t+2 while computing t -> steady-state wait is vmcnt(NLD), never 0.
// LDS 16B-slot swizzle: slot' = slot ^ ((row>>1)&3); applied on global SOURCE
// (linear global_load_lds dest) and on the ds_read address (both-sides rule).
template <int MREP>
__global__ __launch_bounds__(512, 2) void gemm_nt_pipe(
    const unsigned short* __restrict__ A, const unsigned short* __restrict__ Bt,
    const float* __restrict__ bias, unsigned short* __restrict__ C,
    int K, int N, int NBN) {
  constexpr int BM  = MREP * 32;
  constexpr int AI  = MREP / 4;        // A stage-loads per thread per tile
  constexpr int ASH = MREP * 1024;     // A tile size in shorts
  constexpr int NLD = AI + 2;          // loads per thread per tile
  __shared__ unsigned short lds[3 * ASH + 3 * 8192];

  const int tid = threadIdx.x;
  const int w = tid >> 6, l = tid & 63;
  const int lr = l & 15, kg = l >> 4;
  const int wm = w >> 2, wn = w & 3;

  // XCD-aware block swizzle (gridDim.x % 8 == 0), bn-major within chunk
  int swz = (blockIdx.x & 7) * ((int)gridDim.x >> 3) + ((int)blockIdx.x >> 3);
  const int bm = swz / NBN, bn = swz - bm * NBN;
  const int NT = K >> 5;

  // ---- staging source addresses (pre-swizzled slot) ----
  const int rg = l >> 2;                             // row within 16-row group
  const int sl = ((l & 3) ^ ((l >> 3) & 3)) * 8;     // swizzled col-slot * 8
  const unsigned short* ga[AI];
#pragma unroll
  for (int i = 0; i < AI; ++i)
    ga[i] = A + (size_t)(bm * BM + (i * 8 + w) * 16 + rg) * K + sl;
  const unsigned short* gb[2];
#pragma unroll
  for (int j = 0; j < 2; ++j)
    gb[j] = Bt + (size_t)(bn * 256 + (j * 8 + w) * 16 + rg) * K + sl;

  // ---- LDS frag-read byte offsets (swizzled) ----
  const int xo = (kg ^ ((lr >> 1) & 3)) << 4;
  const int aoff = (wm * (MREP * 16) + lr) * 64 + xo;   // + mi*1024
  const int boff = (wn * 64 + lr) * 64 + xo;            // + ni*1024

  f32x4 acc[MREP][4] = {};

  auto stage = [&](int t, int rbuf) {
    unsigned short* la = lds + rbuf * ASH + w * 512;            // wave-uniform
    unsigned short* lb = lds + 3 * ASH + rbuf * 8192 + w * 512; // wave-uniform
    const int ko = t * 32;
#pragma unroll
    for (int i = 0; i < AI; ++i) gld_lds16(ga[i] + ko, la + i * 4096);
    gld_lds16(gb[0] + ko, lb);
    gld_lds16(gb[1] + ko, lb + 4096);
  };

  stage(0, 0);
  stage(1, 1);
  if constexpr (NLD == 4) asm volatile("s_waitcnt vmcnt(4)" ::: "memory");
  else                    asm volatile("s_waitcnt vmcnt(3)" ::: "memory");
  __builtin_amdgcn_s_barrier();
  __builtin_amdgcn_sched_barrier(0);

  int rb = 0;
  for (int t = 0; t < NT; ++t) {
    int rb2 = rb + 2; if (rb2 >= 3) rb2 -= 3;
    if (t + 2 < NT) stage(t + 2, rb2);

    const char* pa = (const char*)lds + rb * (ASH * 2) + aoff;
    const char* pb = (const char*)lds + 6 * ASH + rb * 16384 + boff;
    short8 a[MREP], b[4];
#pragma unroll
    for (int mi = 0; mi < MREP; ++mi) a[mi] = *(const short8*)(pa + mi * 1024);
#pragma unroll
    for (int ni = 0; ni < 4; ++ni)   b[ni] = *(const short8*)(pb + ni * 1024);

    __builtin_amdgcn_s_setprio(1);
#pragma unroll
    for (int mi = 0; mi < MREP; ++mi)
#pragma unroll
      for (int ni = 0; ni < 4; ++ni)
        acc[mi][ni] = __builtin_amdgcn_mfma_f32_16x16x32_bf16(
            a[mi], b[ni], acc[mi][ni], 0, 0, 0);
    __builtin_amdgcn_s_setprio(0);

    __builtin_amdgcn_sched_barrier(0);
    asm volatile("s_waitcnt lgkmcnt(0)" ::: "memory");
    if (t + 2 < NT) {
      if constexpr (NLD == 4) asm volatile("s_waitcnt vmcnt(4)" ::: "memory");
      else                    asm volatile("s_waitcnt vmcnt(3)" ::: "memory");
      __builtin_amdgcn_s_barrier();
    } else if (t + 1 < NT) {
      asm volatile("s_waitcnt vmcnt(0)" ::: "memory");
      __builtin_amdgcn_s_barrier();
    }
    __builtin_amdgcn_sched_barrier(0);

    rb = rb + 1; if (rb >= 3) rb = 0;
  }

  // epilogue: bias + relu + bf16 store.  D: col=lane&15, row=(lane>>4)*4+j
#pragma unroll
  for (int mi = 0; mi < MREP; ++mi) {
    const int row0 = bm * BM + wm * (MREP * 16) + mi * 16 + kg * 4;
#pragma unroll
    for (int ni = 0; ni < 4; ++ni) {
      const int col = bn * 256 + wn * 64 + ni * 16 + lr;
      const float bv = bias[col];
#pragma unroll
      for (int j = 0; j < 4; ++j) {
        float v = acc[mi][ni][j] + bv;
        v = v > 0.f ? v : 0.f;
        C[(size_t)(row0 + j) * N + col] = f2bf(v);
      }
    }
  }
}

// ---- routed expert head: one wave per sample, fp32 vector math ----
__global__ __launch_bounds__(256) void expert_head(
    const unsigned short* __restrict__ h1, const float* __restrict__ We,
    const float* __restrict__ be, const int* __restrict__ ballot,
    const int* __restrict__ contest, float* __restrict__ out) {
  int b = blockIdx.x * 4 + (threadIdx.x >> 6);
  int lane = threadIdx.x & 63;
  int o = lane & 31, half = lane >> 5;
  int e = ballot[b] * 8 + contest[b];
  const unsigned short* hrow = h1 + (size_t)b * H1D + half * 512;
  const float* wb = We + ((size_t)e * H1D + half * 512) * 32 + o;
  float acc = 0.f;
  for (int d0 = 0; d0 < 512; d0 += 8) {
    short8 hv = *reinterpret_cast<const short8*>(&hrow[d0]);
#pragma unroll
    for (int j = 0; j < 8; ++j)
      acc = fmaf(bf2f((unsigned short)hv[j]), wb[(size_t)(d0 + j) * 32], acc);
  }
  acc += __shfl_xor(acc, 32, 64);
  if (half == 0) {
    float x = acc + be[e * 32 + o];
    out[(size_t)b * 32 + o] = 1.f / (1.f + expf(-x));
  }
}

extern "C" void kernel_launch(void* const* d_in, const int* in_sizes, int n_in,
                              void* d_out, int out_size, void* d_ws, size_t ws_size,
                              hipStream_t stream) {
  const float* inputs = (const float*)d_in[0];
  const float* emb    = (const float*)d_in[1];
  const float* W0     = (const float*)d_in[2];
  const float* b0     = (const float*)d_in[3];
  const float* W1     = (const float*)d_in[4];
  const float* b1     = (const float*)d_in[5];
  const float* We     = (const float*)d_in[6];
  const float* be     = (const float*)d_in[7];
  const int* ballot   = (const int*)d_in[8];
  const int* contest  = (const int*)d_in[9];
  float* out = (float*)d_out;

  char* ws = (char*)d_ws;
  unsigned short* A   = (unsigned short*)(ws);                 //  67108864 B
  unsigned short* W0t = (unsigned short*)(ws + 67108864);      //  16777216 B
  unsigned short* h0  = (unsigned short*)(ws + 83886080);      //  33554432 B
  unsigned short* W1t = (unsigned short*)(ws + 117440512);     //   4194304 B
  unsigned short* h1  = (unsigned short*)(ws + 121634816);     //  16777216 B
  // total 138412032 B

  dim3 blk(256);
  // W0 [4096][2048] -> W0t [2048][4096]
  transpose_cvt<<<dim3(H0D / 32, KDIM / 32, 1), blk, 0, stream>>>(W0, W0t, KDIM, H0D);
  // W1 [2048][1024] -> W1t [1024][2048]
  transpose_cvt<<<dim3(H1D / 32, H0D / 32, 1), blk, 0, stream>>>(W1, W1t, H0D, H1D);
  build_A<<<dim3(B_SZ * 512 / 256), blk, 0, stream>>>(inputs, emb, ballot, contest, A);
  // GEMM1: [8192 x 4096] x [2048 x 4096]^T, 256x256 tiles -> 32*8 = 256 blocks
  gemm_nt_pipe<8><<<dim3((B_SZ / 256) * (H0D / 256)), dim3(512), 0, stream>>>(
      A, W0t, b0, h0, KDIM, H0D, H0D / 256);
  // GEMM2: [8192 x 2048] x [1024 x 2048]^T, 128x256 tiles -> 64*4 = 256 blocks
  gemm_nt_pipe<4><<<dim3((B_SZ / 128) * (H1D / 256)), dim3(512), 0, stream>>>(
      h0, W1t, b1, h1, H0D, H1D, H1D / 256);
  expert_head<<<dim3(B_SZ / 4), blk, 0, stream>>>(h1, We, be, ballot, contest, out);
}

// Round 2
// 264.302 us; speedup vs baseline: 1.3309x; 1.0035x over previous
//
#include <hip/hip_runtime.h>
#include <math.h>

typedef __attribute__((ext_vector_type(8))) short short8;
typedef __attribute__((ext_vector_type(4))) float f32x4;

#define B_SZ 8192
#define D_INN 4000
#define EMBD 96
#define H0D 2048
#define H1D 1024
#define KDIM 4096  // EMB + D_IN

__device__ __forceinline__ unsigned short f2bf(float f) {
  union { float f; unsigned u; } v; v.f = f;
  unsigned r = v.u + 0x7FFFu + ((v.u >> 16) & 1u);
  return (unsigned short)(r >> 16);
}
__device__ __forceinline__ float bf2f(unsigned short h) {
  union { unsigned u; float f; } v; v.u = ((unsigned)h) << 16;
  return v.f;
}
__device__ __forceinline__ void gld_lds16(const void* g, void* l) {
  __builtin_amdgcn_global_load_lds(
      (const __attribute__((address_space(1))) unsigned int*)g,
      (__attribute__((address_space(3))) unsigned int*)l, 16, 0, 0);
}

// ---- transpose + fp32->bf16 convert: out[c][r] = bf16(in[r][c]) ----
__global__ __launch_bounds__(256) void transpose_cvt(
    const float* __restrict__ in, unsigned short* __restrict__ out, int R, int C) {
  __shared__ float tile[32][33];
  int c0 = blockIdx.x * 32, r0 = blockIdx.y * 32;
  int tc = threadIdx.x & 31, tr = threadIdx.x >> 5;
#pragma unroll
  for (int i = 0; i < 4; ++i) {
    int r = tr + i * 8;
    tile[r][tc] = in[(size_t)(r0 + r) * C + (c0 + tc)];
  }
  __syncthreads();
#pragma unroll
  for (int i = 0; i < 4; ++i) {
    int rr = tr + i * 8;
    out[(size_t)(c0 + rr) * R + (r0 + tc)] = f2bf(tile[tc][rr]);
  }
}

// ---- build A = [emb_gather | inputs] in bf16, vectorized 8-wide ----
__global__ __launch_bounds__(256) void build_A(
    const float* __restrict__ inputs, const float* __restrict__ emb,
    const int* __restrict__ ballot, const int* __restrict__ contest,
    unsigned short* __restrict__ A) {
  int gid = blockIdx.x * 256 + threadIdx.x;   // chunk of 8 elems
  int b = gid >> 9, c = gid & 511;            // 512 chunks per row of 4096
  const float* src;
  if (c < EMBD / 8) {
    int e = ballot[b] * 8 + contest[b];
    src = emb + (size_t)e * EMBD + c * 8;
  } else {
    src = inputs + (size_t)b * D_INN + (c - EMBD / 8) * 8;
  }
  float4 v0 = *(const float4*)src;
  float4 v1 = *(const float4*)(src + 4);
  unsigned short r[8];
  r[0] = f2bf(v0.x); r[1] = f2bf(v0.y); r[2] = f2bf(v0.z); r[3] = f2bf(v0.w);
  r[4] = f2bf(v1.x); r[5] = f2bf(v1.y); r[6] = f2bf(v1.z); r[7] = f2bf(v1.w);
  *reinterpret_cast<short8*>(A + (size_t)b * KDIM + c * 8) =
      *reinterpret_cast<const short8*>(r);
}

// ---- NT bf16 MFMA GEMM, ring-3 pipelined, two-phase interleave ----
// BN = 256; BM = MREP*32; BK = 32. 8 waves = 2(M) x 4(N), 512 threads.
// Ring-3 LDS K-tiles; stage t+2 while computing t; steady-state wait is
// vmcnt(NLD) (never 0 mid-loop). Per tile, TWO phases:
//   phase A: ds_read {A mi<MH, B ni0-3}, stageA(t+2), lgkm(0), barrier, 16 MFMA
//   phase B: ds_read {A mi>=MH},        stageB(t+2), lgkm(0), vmcnt(N), barrier, 16 MFMA
// so each phase's LDS reads/waits overlap the previous phase's MFMA drain.
// Slot-overwrite safety: every stage into slot s is >=1 barrier after a
// per-wave lgkmcnt(0) that retires the last reads of s.
template <int MREP>
__global__ __launch_bounds__(512, 2) void gemm_nt_pipe(
    const unsigned short* __restrict__ A, const unsigned short* __restrict__ Bt,
    const float* __restrict__ bias, unsigned short* __restrict__ C,
    int K, int N, int NBN) {
  constexpr int BM  = MREP * 32;
  constexpr int AI  = MREP / 4;        // A stage-loads per thread per tile (2|1)
  constexpr int ASH = BM * 32;         // A tile size in shorts
  constexpr int MH  = MREP / 2;        // mi per phase
  __shared__ unsigned short lds[3 * ASH + 3 * 8192];

  const int tid = threadIdx.x;
  const int w = tid >> 6, l = tid & 63;
  const int lr = l & 15, kg = l >> 4;
  const int wm = w >> 2, wn = w & 3;

  // XCD-aware block swizzle (gridDim.x % 8 == 0), bn-major within chunk
  int swz = (blockIdx.x & 7) * ((int)gridDim.x >> 3) + ((int)blockIdx.x >> 3);
  const int bm = swz / NBN, bn = swz - bm * NBN;
  const int NT = K >> 5;

  // ---- staging source addresses (pre-swizzled slot) ----
  const int rg = l >> 2;                             // row within 16-row group
  const int sl = ((l & 3) ^ ((l >> 3) & 3)) * 8;     // swizzled col-slot * 8
  const unsigned short* ga[AI];
#pragma unroll
  for (int i = 0; i < AI; ++i)
    ga[i] = A + (size_t)(bm * BM + (i * 8 + w) * 16 + rg) * K + sl;
  const unsigned short* gb0 = Bt + (size_t)(bn * 256 + w * 16 + rg) * K + sl;
  const unsigned short* gb1 = gb0 + (size_t)128 * K;

  // ---- LDS frag-read byte offsets (swizzled) ----
  const int xo = (kg ^ ((lr >> 1) & 3)) << 4;
  const int aoff = (wm * (MREP * 16) + lr) * 64 + xo;   // + mi*1024
  const int boff = (wn * 64 + lr) * 64 + xo;            // + ni*1024

  f32x4 acc[MREP][4] = {};

  auto stageA = [&](int t, int rbuf) {
    unsigned short* la = lds + rbuf * ASH + w * 512;   // wave-uniform base
    const int ko = t * 32;
#pragma unroll
    for (int i = 0; i < AI; ++i) gld_lds16(ga[i] + ko, la + i * 4096);
  };
  auto stageB = [&](int t, int rbuf) {
    unsigned short* lb = lds + 3 * ASH + rbuf * 8192 + w * 512;
    const int ko = t * 32;
    gld_lds16(gb0 + ko, lb);
    gld_lds16(gb1 + ko, lb + 4096);
  };

#define WAIT_VM_STEADY() do { \
    if constexpr (AI == 2) asm volatile("s_waitcnt vmcnt(4)" ::: "memory"); \
    else                   asm volatile("s_waitcnt vmcnt(3)" ::: "memory"); \
  } while (0)

  stageA(0, 0); stageB(0, 0);
  stageA(1, 1); stageB(1, 1);
  WAIT_VM_STEADY();                     // tile 0 landed; tile 1 in flight
  __builtin_amdgcn_s_barrier();

  int rb = 0;
  for (int t = 0; t < NT; ++t) {
    int rb2 = rb + 2; if (rb2 >= 3) rb2 -= 3;
    const char* pa = (const char*)lds + rb * (ASH * 2) + aoff;
    const char* pb = (const char*)lds + 3 * (ASH * 2) + rb * 16384 + boff;

    // ---------- phase A: {mi 0..MH-1} x {ni 0..3} ----------
    short8 a0[MH], bfr[4];
#pragma unroll
    for (int mi = 0; mi < MH; ++mi) a0[mi] = *(const short8*)(pa + mi * 1024);
#pragma unroll
    for (int ni = 0; ni < 4; ++ni)  bfr[ni] = *(const short8*)(pb + ni * 1024);
    if (t + 2 < NT) stageA(t + 2, rb2);
    asm volatile("s_waitcnt lgkmcnt(0)" ::: "memory");
    __builtin_amdgcn_s_barrier();
    __builtin_amdgcn_s_setprio(1);
#pragma unroll
    for (int mi = 0; mi < MH; ++mi)
#pragma unroll
      for (int ni = 0; ni < 4; ++ni)
        acc[mi][ni] = __builtin_amdgcn_mfma_f32_16x16x32_bf16(
            a0[mi], bfr[ni], acc[mi][ni], 0, 0, 0);
    __builtin_amdgcn_s_setprio(0);

    // ---------- phase B: {mi MH..MREP-1} x {ni 0..3} ----------
    short8 a1[MH];
#pragma unroll
    for (int mi = 0; mi < MH; ++mi) a1[mi] = *(const short8*)(pa + (MH + mi) * 1024);
    if (t + 2 < NT) {
      stageB(t + 2, rb2);
      asm volatile("s_waitcnt lgkmcnt(0)" ::: "memory");
      WAIT_VM_STEADY();                 // tile t+1 landed; t+2 stays in flight
      __builtin_amdgcn_s_barrier();
    } else if (t + 1 < NT) {
      asm volatile("s_waitcnt lgkmcnt(0)" ::: "memory");
      asm volatile("s_waitcnt vmcnt(0)" ::: "memory");
      __builtin_amdgcn_s_barrier();
    } else {
      asm volatile("s_waitcnt lgkmcnt(0)" ::: "memory");
    }
    __builtin_amdgcn_s_setprio(1);
#pragma unroll
    for (int mi = 0; mi < MH; ++mi)
#pragma unroll
      for (int ni = 0; ni < 4; ++ni)
        acc[MH + mi][ni] = __builtin_amdgcn_mfma_f32_16x16x32_bf16(
            a1[mi], bfr[ni], acc[MH + mi][ni], 0, 0, 0);
    __builtin_amdgcn_s_setprio(0);

    rb = rb + 1; if (rb >= 3) rb = 0;
  }

  // epilogue: bias + relu + bf16 store.  D: col=lane&15, row=(lane>>4)*4+j
#pragma unroll
  for (int mi = 0; mi < MREP; ++mi) {
    const int row0 = bm * BM + wm * (MREP * 16) + mi * 16 + kg * 4;
#pragma unroll
    for (int ni = 0; ni < 4; ++ni) {
      const int col = bn * 256 + wn * 64 + ni * 16 + lr;
      const float bv = bias[col];
#pragma unroll
      for (int j = 0; j < 4; ++j) {
        float v = acc[mi][ni][j] + bv;
        v = v > 0.f ? v : 0.f;
        C[(size_t)(row0 + j) * N + col] = f2bf(v);
      }
    }
  }
#undef WAIT_VM_STEADY
}

// ---- routed expert head: one wave per sample, fp32 vector math ----
__global__ __launch_bounds__(256) void expert_head(
    const unsigned short* __restrict__ h1, const float* __restrict__ We,
    const float* __restrict__ be, const int* __restrict__ ballot,
    const int* __restrict__ contest, float* __restrict__ out) {
  int b = blockIdx.x * 4 + (threadIdx.x >> 6);
  int lane = threadIdx.x & 63;
  int o = lane & 31, half = lane >> 5;
  int e = ballot[b] * 8 + contest[b];
  const unsigned short* hrow = h1 + (size_t)b * H1D + half * 512;
  const float* wb = We + ((size_t)e * H1D + half * 512) * 32 + o;
  float acc = 0.f;
  for (int d0 = 0; d0 < 512; d0 += 8) {
    short8 hv = *reinterpret_cast<const short8*>(&hrow[d0]);
#pragma unroll
    for (int j = 0; j < 8; ++j)
      acc = fmaf(bf2f((unsigned short)hv[j]), wb[(size_t)(d0 + j) * 32], acc);
  }
  acc += __shfl_xor(acc, 32, 64);
  if (half == 0) {
    float x = acc + be[e * 32 + o];
    out[(size_t)b * 32 + o] = 1.f / (1.f + expf(-x));
  }
}

extern "C" void kernel_launch(void* const* d_in, const int* in_sizes, int n_in,
                              void* d_out, int out_size, void* d_ws, size_t ws_size,
                              hipStream_t stream) {
  const float* inputs = (const float*)d_in[0];
  const float* emb    = (const float*)d_in[1];
  const float* W0     = (const float*)d_in[2];
  const float* b0     = (const float*)d_in[3];
  const float* W1     = (const float*)d_in[4];
  const float* b1     = (const float*)d_in[5];
  const float* We     = (const float*)d_in[6];
  const float* be     = (const float*)d_in[7];
  const int* ballot   = (const int*)d_in[8];
  const int* contest  = (const int*)d_in[9];
  float* out = (float*)d_out;

  char* ws = (char*)d_ws;
  unsigned short* A   = (unsigned short*)(ws);                 //  67108864 B
  unsigned short* W0t = (unsigned short*)(ws + 67108864);      //  16777216 B
  unsigned short* h0  = (unsigned short*)(ws + 83886080);      //  33554432 B
  unsigned short* W1t = (unsigned short*)(ws + 117440512);     //   4194304 B
  unsigned short* h1  = (unsigned short*)(ws + 121634816);     //  16777216 B
  // total 138412032 B

  dim3 blk(256);
  // W0 [4096][2048] -> W0t [2048][4096]
  transpose_cvt<<<dim3(H0D / 32, KDIM / 32, 1), blk, 0, stream>>>(W0, W0t, KDIM, H0D);
  // W1 [2048][1024] -> W1t [1024][2048]
  transpose_cvt<<<dim3(H1D / 32, H0D / 32, 1), blk, 0, stream>>>(W1, W1t, H0D, H1D);
  build_A<<<dim3(B_SZ * 512 / 256), blk, 0, stream>>>(inputs, emb, ballot, contest, A);
  // GEMM1: [8192 x 4096] x [2048 x 4096]^T, 256x256 tiles -> 32*8 = 256 blocks
  gemm_nt_pipe<8><<<dim3((B_SZ / 256) * (H0D / 256)), dim3(512), 0, stream>>>(
      A, W0t, b0, h0, KDIM, H0D, H0D / 256);
  // GEMM2: [8192 x 2048] x [1024 x 2048]^T, 128x256 tiles -> 64*4 = 256 blocks
  gemm_nt_pipe<4><<<dim3((B_SZ / 128) * (H1D / 256)), dim3(512), 0, stream>>>(
      h0, W1t, b1, h1, H0D, H1D, H1D / 256);
  expert_head<<<dim3(B_SZ / 4), blk, 0, stream>>>(h1, We, be, ballot, contest, out);
}